// Round 13
// baseline (105.804 us; speedup 1.0000x reference)
//
#include <hip/hip_runtime.h>
#include <hip/hip_bf16.h>

#define NFFT    512
#define HOPSZ   128
#define FBINS   257
#define TFR     2048
#define NBC     32            // B*C
#define OUTLEN  262016        // (T-1)*HOP
#define SPAD    256           // n_fft/2 (center trim)
#define NPANEL  17            // stride-125 panels of 128 frames
#define PSTR    125           // panel stride (128-tile, 3 overlap)
#define FROW    532           // F row stride in bf16

typedef __bf16 bf16x8 __attribute__((ext_vector_type(8)));
typedef float  f32x4  __attribute__((ext_vector_type(4)));

static __device__ __forceinline__ float bf2f(unsigned short u) {
    union { unsigned int i; float f; } x; x.i = (unsigned int)u << 16; return x.f;
}

__device__ __forceinline__ void gld_lds16(const void* g, void* l) {
    __builtin_amdgcn_global_load_lds(
        (const __attribute__((address_space(1))) unsigned int*)g,
        (__attribute__((address_space(3))) unsigned int*)l, 16, 0, 0);
}

// ---------------------------------------------------------------------------
// Kernel 1: W' in MFMA A-fragment order (verified R2-R12).
//   Wf[(ks*32 + rt)*64 + lane]: 8 bf16, elem j:
//     n = rt*16 + (lane&15),  k = ks*32 + 4*(lane>>4) + (j&3) + 16*(j>>2)
// ---------------------------------------------------------------------------
__global__ __launch_bounds__(256) void k_wgen(const float* __restrict__ wnd,
                                              uint4* __restrict__ Wf) {
    const int gid  = blockIdx.x * 256 + threadIdx.x;   // < 34816
    const int lane = gid & 63;
    const int rt   = (gid >> 6) & 31;
    const int ks   = gid >> 11;
    const int n    = rt * 16 + (lane & 15);
    const int kb   = ks * 32 + ((lane >> 4) << 2);
    const float wn = wnd[n] * (1.0f / 512.0f);
    union { uint4 u; unsigned short h[8]; } o;
    #pragma unroll
    for (int j = 0; j < 8; ++j) {
        const int k = kb + (j & 3) + 16 * (j >> 2);
        float val = 0.0f;
        if (k < 2 * FBINS) {
            const int f = k >> 1;
            const bool edge = (f == 0) || (f == 256);
            const float cf = edge ? 1.0f : 2.0f;
            const int m = (f * n) & (NFFT - 1);
            const float ang = (float)m * 0.01227184630308513f; // 2*pi/512
            float s, c;
            __sincosf(ang, &s, &c);
            val = (k & 1) ? (edge ? 0.0f : -cf * wn * s) : (cf * wn * c);
        }
        __hip_bfloat16 hb = __float2bfloat16(val);
        o.h[j] = *(unsigned short*)&hb;
    }
    Wf[gid] = o.u;
}

// ---------------------------------------------------------------------------
// Kernel 2 (FUSED): GEMM + in-LDS overlap-add.  R12 core, BN 64 -> 128.
//   544 blocks = 32 bc x 17 panels; panel p -> frames [125p, 125p+128).
//   A-DMA halves chip-wide (612 -> 278 MB): the staged-bytes binder.
//   LDS union (139 KB, 1 block/CU): staging {Ab 64K | Bb 16K} then
//   post {F[128][FROW] 136K | XreL 512B | wL 2K}.
// ---------------------------------------------------------------------------
__global__ __launch_bounds__(512, 2) void k_fused(
    const float* __restrict__ X,
    const uint4* __restrict__ Wf,
    const float* __restrict__ wnd,
    float* __restrict__ out)
{
    __shared__ __align__(16) char smem[139264];
    uint4* Ab  = (uint4*)smem;                        // [2][32][64] 64 KB
    uint4* Bb4 = (uint4*)(smem + 65536);              // [2][4][128] 16 KB
    unsigned int* BbU = (unsigned int*)(smem + 65536);
    float* XreL = (float*)(smem + 136192);            // 128 floats
    float* wL   = (float*)(smem + 136704);            // 512 floats

    const int tid  = threadIdx.x;
    const int lane = tid & 63;
    const int w    = tid >> 6;        // wave -> rows [64w, +64)
    const int q    = lane >> 4;
    const int rlo  = lane & 15;

    const int bid = blockIdx.x;       // 544 = 8 XCD-chunks of 68
    const int id  = (bid & 7) * 68 + (bid >> 3);
    const int panel = id % NPANEL;
    const int bc    = id / NPANEL;    // 0..31
    const int tp    = panel * PSTR;   // frame base

    const float2* __restrict__ X2 = (const float2*)X + (size_t)bc * FBINS * TFR;

    // B staging roles (R7/R12-verified): sf = f_local 0..31, st = t-slot 0..15
    const int sf  = tid >> 4;
    const int st  = tid & 15;
    const int r2  = (2 * sf) & 31;
    const int skk = sf >> 4;
    const int sq  = (r2 & 15) >> 2;
    const int sj  = ((r2 & 2) >> 1) + (((r2 >> 4) & 1) << 1);

    f32x4 acc[4][8] = {};

    // ================= GEMM phase =================
    for (int ks = 0; ks < 8; ++ks) {
        __syncthreads();
        // --- B loads first (8x 8B; t clamped for last panel) ---
        float2 xv[8];
        #pragma unroll
        for (int d = 0; d < 8; ++d) {
            int t = tp + st + (d << 4);
            t = (t < TFR) ? t : (TFR - 1);             // garbage rows masked in OLA
            xv[d] = X2[(size_t)(ks * 32 + sf) * TFR + t];
        }
        // --- A: 8x global_load_lds dwordx4 (2 slabs of 32 KB) ---
        #pragma unroll
        for (int s = 0; s < 2; ++s) {
            const uint4* src = Wf + (size_t)(2 * ks + s) * 2048;
            uint4* dst = Ab + s * 2048;
            #pragma unroll
            for (int r = 0; r < 4; ++r)
                gld_lds16(src + r * 512 + tid, dst + r * 512 + tid);
        }
        // --- B pack + LDS writes (verified mapping; t-extent 128) ---
        #pragma unroll
        for (int d = 0; d < 8; ++d) {
            union { unsigned int u; __hip_bfloat16 h[2]; } p;
            p.h[0] = __float2bfloat16(xv[d].x);
            p.h[1] = __float2bfloat16(xv[d].y);
            BbU[(((((skk << 2) + sq) << 7) + st + (d << 4)) << 2) + sj] = p.u;
        }
        __syncthreads();
        // --- compute: 64 MFMA / wave ---
        #pragma unroll
        for (int kk = 0; kk < 2; ++kk) {
            uint4 a[4], b[8];
            #pragma unroll
            for (int ni = 0; ni < 8; ++ni) b[ni] = Bb4[(kk * 4 + q) * 128 + ni * 16 + rlo];
            #pragma unroll
            for (int mi = 0; mi < 4; ++mi) a[mi] = Ab[(kk * 32 + 4 * w + mi) * 64 + lane];
            #pragma unroll
            for (int mi = 0; mi < 4; ++mi)
                #pragma unroll
                for (int ni = 0; ni < 8; ++ni)
                    acc[mi][ni] = __builtin_amdgcn_mfma_f32_16x16x32_bf16(
                        __builtin_bit_cast(bf16x8, a[mi]),
                        __builtin_bit_cast(bf16x8, b[ni]), acc[mi][ni], 0, 0, 0);
        }
    }

    // ================= acc -> F (LDS), stage Xre/wnd =================
    __syncthreads();                  // all staging reads done before union reuse
    #pragma unroll
    for (int mi = 0; mi < 4; ++mi) {
        const int n = (w << 6) + (mi << 4) + (q << 2);
        #pragma unroll
        for (int ni = 0; ni < 8; ++ni) {
            const int lt = ni * 16 + rlo;              // frame t = tp + lt (C/D col)
            union { ushort4 u; __hip_bfloat16 hh[4]; } pk;
            pk.hh[0] = __float2bfloat16(acc[mi][ni][0]);
            pk.hh[1] = __float2bfloat16(acc[mi][ni][1]);
            pk.hh[2] = __float2bfloat16(acc[mi][ni][2]);
            pk.hh[3] = __float2bfloat16(acc[mi][ni][3]);
            *(ushort4*)((unsigned short*)(smem + lt * (FROW * 2)) + n) = pk.u;
        }
    }
    if (tid < 128) {                  // DC term source: re(X[256, tp+lt])
        int t = tp + tid;
        t = (t < TFR) ? t : (TFR - 1);
        XreL[tid] = X2[(size_t)256 * TFR + t].x;
    }
    wL[tid & 511] = wnd[tid & 511];   // 512 threads, 512 floats
    __syncthreads();

    // ================= OLA + envelope normalize (R12-verified math) =====
    const int olo = (panel == 0) ? 0 : tp * 128 + 128;
    const int ohi = (panel == NPANEL - 1) ? OUTLEN : tp * 128 + 16128;
    float* outb = out + (size_t)bc * OUTLEN;
    for (int o = olo + tid; o < ohi; o += 512) {
        const int s  = o + SPAD;
        const int tb = s >> 7;
        const int nb = s & (HOPSZ - 1);
        const float sg = (s & 1) ? (-1.0f / 512.0f) : (1.0f / 512.0f);
        float y = 0.f, e = 0.f;
        #pragma unroll
        for (int r = 0; r < 4; ++r) {
            const int t  = tb - r;
            const int lt = t - tp;
            if ((unsigned)lt >= 128u || (unsigned)t >= (unsigned)TFR) continue;
            const int n = nb + (r << 7);
            const float wv = wL[n];
            const float fv = bf2f(*((const unsigned short*)(smem + lt * (FROW * 2)) + n));
            y += fv + sg * XreL[lt] * wv;
            e += wv * wv;
        }
        outb[o] = y / e;
    }
}

// ---------------------------------------------------------------------------
extern "C" void kernel_launch(void* const* d_in, const int* in_sizes, int n_in,
                              void* d_out, int out_size, void* d_ws, size_t ws_size,
                              hipStream_t stream) {
    (void)in_sizes; (void)n_in; (void)out_size; (void)ws_size;
    const float* X   = (const float*)d_in[0];
    const float* wnd = (const float*)d_in[1];
    float* out = (float*)d_out;

    uint4* Wf = (uint4*)d_ws;                                            // 544 KB

    k_wgen<<<136, 256, 0, stream>>>(wnd, Wf);
    k_fused<<<NBC * NPANEL, 512, 0, stream>>>(X, Wf, wnd, out);
}

// Round 14
// 71.627 us; speedup vs baseline: 1.4771x; 1.4771x over previous
//
#include <hip/hip_runtime.h>
#include <hip/hip_bf16.h>

#define NFFT    512
#define HOPSZ   128
#define FBINS   257
#define TFR     2048
#define NBC     32            // B*C
#define OUTLEN  262016        // (T-1)*HOP
#define SPAD    256           // n_fft/2 (center trim)
#define NPANEL  34            // stride-61 panels of 64 frames
#define PSTR    61            // panel stride (64-tile, 3 overlap)
#define FROW    532           // F row stride in bf16 (1064 B)

typedef __bf16 bf16x8 __attribute__((ext_vector_type(8)));
typedef float  f32x4  __attribute__((ext_vector_type(4)));

static __device__ __forceinline__ float bf2f(unsigned short u) {
    union { unsigned int i; float f; } x; x.i = (unsigned int)u << 16; return x.f;
}

__device__ __forceinline__ void gld_lds16(const void* g, void* l) {
    __builtin_amdgcn_global_load_lds(
        (const __attribute__((address_space(1))) unsigned int*)g,
        (__attribute__((address_space(3))) unsigned int*)l, 16, 0, 0);
}

// ---------------------------------------------------------------------------
// Kernel 1: W' in MFMA A-fragment order (verified R2-R13).
//   Wf[(ks*32 + rt)*64 + lane]: 8 bf16, elem j:
//     n = rt*16 + (lane&15),  k = ks*32 + 4*(lane>>4) + (j&3) + 16*(j>>2)
// ---------------------------------------------------------------------------
__global__ __launch_bounds__(256) void k_wgen(const float* __restrict__ wnd,
                                              uint4* __restrict__ Wf) {
    const int gid  = blockIdx.x * 256 + threadIdx.x;   // < 34816
    const int lane = gid & 63;
    const int rt   = (gid >> 6) & 31;
    const int ks   = gid >> 11;
    const int n    = rt * 16 + (lane & 15);
    const int kb   = ks * 32 + ((lane >> 4) << 2);
    const float wn = wnd[n] * (1.0f / 512.0f);
    union { uint4 u; unsigned short h[8]; } o;
    #pragma unroll
    for (int j = 0; j < 8; ++j) {
        const int k = kb + (j & 3) + 16 * (j >> 2);
        float val = 0.0f;
        if (k < 2 * FBINS) {
            const int f = k >> 1;
            const bool edge = (f == 0) || (f == 256);
            const float cf = edge ? 1.0f : 2.0f;
            const int m = (f * n) & (NFFT - 1);
            const float ang = (float)m * 0.01227184630308513f; // 2*pi/512
            float s, c;
            __sincosf(ang, &s, &c);
            val = (k & 1) ? (edge ? 0.0f : -cf * wn * s) : (cf * wn * c);
        }
        __hip_bfloat16 hb = __float2bfloat16(val);
        o.h[j] = *(unsigned short*)&hb;
    }
    Wf[gid] = o.u;
}

// ---------------------------------------------------------------------------
// Kernel 2 (FUSED): GEMM (R7/R12 core verbatim) + in-LDS overlap-add.
//   1088 blocks = 32 bc x 34 panels; panel p -> frames [61p, 61p+64).
//   NEW vs R12: interior panels (1..32) use a periodic envelope-reciprocal
//   table E[128] (all 4 taps always valid by stride-61 construction) and a
//   float4-group OLA: per 4 aligned outputs, tb is shared and nb<=124 so
//   each tap is ONE ushort4 F-read + ONE float4 w-read; store is float4.
//   Edge panels (0, 33) keep the R12 scalar path (boundary masking).
//   LDS union (72 KB, 2 blocks/CU): staging {Ab 64K | Bb 8K} then post
//   {F[64][FROW] 67.8K | XreL 256B | wL 2K | Ercp 512B}.
// ---------------------------------------------------------------------------
__global__ __launch_bounds__(512, 4) void k_fused(
    const float* __restrict__ X,
    const uint4* __restrict__ Wf,
    const float* __restrict__ wnd,
    float* __restrict__ out)
{
    __shared__ __align__(16) char smem[73728];
    uint4* Ab  = (uint4*)smem;                        // [2][32][64] 64 KB
    uint4* Bb4 = (uint4*)(smem + 65536);              // [2][4][64]   8 KB
    unsigned int* BbU = (unsigned int*)(smem + 65536);
    float* XreL  = (float*)(smem + 68096);            // 64 floats
    float* wL    = (float*)(smem + 68352);            // 512 floats
    float* ErcpL = (float*)(smem + 70400);            // 128 floats

    const int tid  = threadIdx.x;
    const int lane = tid & 63;
    const int w    = tid >> 6;        // wave -> rows [64w, +64)
    const int q    = lane >> 4;
    const int rlo  = lane & 15;

    const int bid = blockIdx.x;       // 1088 = 8 XCD-chunks of 136
    const int id  = (bid & 7) * 136 + (bid >> 3);
    const int panel = id % NPANEL;
    const int bc    = id / NPANEL;    // 0..31
    const int tp    = panel * PSTR;   // frame base

    const float2* __restrict__ X2 = (const float2*)X + (size_t)bc * FBINS * TFR;

    // B staging roles (R7/R12-verified): sf = f_local 0..31, st = t-slot 0..15
    const int sf  = tid >> 4;
    const int st  = tid & 15;
    const int r2  = (2 * sf) & 31;
    const int skk = sf >> 4;
    const int sq  = (r2 & 15) >> 2;
    const int sj  = ((r2 & 2) >> 1) + (((r2 >> 4) & 1) << 1);

    f32x4 acc[4][4] = {};

    // ================= GEMM phase (R12 core, verbatim) =================
    for (int ks = 0; ks < 8; ++ks) {
        __syncthreads();
        // --- B loads first (4x 8B; t clamped for last panel) ---
        float2 xv[4];
        #pragma unroll
        for (int d = 0; d < 4; ++d) {
            int t = tp + st + (d << 4);
            t = (t < TFR) ? t : (TFR - 1);             // garbage rows masked in OLA
            xv[d] = X2[(size_t)(ks * 32 + sf) * TFR + t];
        }
        // --- A: 8x global_load_lds dwordx4 (2 slabs of 32 KB) ---
        #pragma unroll
        for (int s = 0; s < 2; ++s) {
            const uint4* src = Wf + (size_t)(2 * ks + s) * 2048;
            uint4* dst = Ab + s * 2048;
            #pragma unroll
            for (int r = 0; r < 4; ++r)
                gld_lds16(src + r * 512 + tid, dst + r * 512 + tid);
        }
        // --- B pack + LDS writes (verified mapping) ---
        #pragma unroll
        for (int d = 0; d < 4; ++d) {
            union { unsigned int u; __hip_bfloat16 h[2]; } p;
            p.h[0] = __float2bfloat16(xv[d].x);
            p.h[1] = __float2bfloat16(xv[d].y);
            BbU[(((((skk << 2) + sq) << 6) + st + (d << 4)) << 2) + sj] = p.u;
        }
        __syncthreads();
        // --- compute: 32 MFMA / wave ---
        #pragma unroll
        for (int kk = 0; kk < 2; ++kk) {
            uint4 a[4], b[4];
            #pragma unroll
            for (int ni = 0; ni < 4; ++ni) b[ni] = Bb4[(kk * 4 + q) * 64 + ni * 16 + rlo];
            #pragma unroll
            for (int mi = 0; mi < 4; ++mi) a[mi] = Ab[(kk * 32 + 4 * w + mi) * 64 + lane];
            #pragma unroll
            for (int mi = 0; mi < 4; ++mi)
                #pragma unroll
                for (int ni = 0; ni < 4; ++ni)
                    acc[mi][ni] = __builtin_amdgcn_mfma_f32_16x16x32_bf16(
                        __builtin_bit_cast(bf16x8, a[mi]),
                        __builtin_bit_cast(bf16x8, b[ni]), acc[mi][ni], 0, 0, 0);
        }
    }

    // ================= acc -> F (LDS), stage Xre/wnd/Ercp =================
    __syncthreads();                  // all staging reads done before union reuse
    #pragma unroll
    for (int mi = 0; mi < 4; ++mi) {
        const int n = (w << 6) + (mi << 4) + (q << 2);
        #pragma unroll
        for (int ni = 0; ni < 4; ++ni) {
            const int lt = ni * 16 + rlo;              // frame t = tp + lt (C/D col)
            union { ushort4 u; __hip_bfloat16 hh[4]; } pk;
            pk.hh[0] = __float2bfloat16(acc[mi][ni][0]);
            pk.hh[1] = __float2bfloat16(acc[mi][ni][1]);
            pk.hh[2] = __float2bfloat16(acc[mi][ni][2]);
            pk.hh[3] = __float2bfloat16(acc[mi][ni][3]);
            *(ushort4*)((unsigned short*)(smem + lt * (FROW * 2)) + n) = pk.u;
        }
    }
    if (tid < 64) {                   // DC term source: re(X[256, tp+lt])
        int t = tp + tid;
        t = (t < TFR) ? t : (TFR - 1);
        XreL[tid] = X2[(size_t)256 * TFR + t].x;
    }
    wL[tid] = wnd[tid];               // 512 threads, 512 floats
    if (tid < 128) {                  // periodic envelope reciprocal (full 4-tap)
        float e = 0.0f;
        #pragma unroll
        for (int r = 0; r < 4; ++r) {
            const float v = wnd[tid + (r << 7)];
            e += v * v;
        }
        ErcpL[tid] = 1.0f / e;
    }
    __syncthreads();

    // ================= OLA + envelope normalize =================
    float* outb = out + (size_t)bc * OUTLEN;
    if (panel != 0 && panel != NPANEL - 1) {
        // interior: all 4 taps valid; 4 aligned outputs/group share tb;
        // nb <= 124 -> each tap is one ushort4 + one float4 read.
        const int olo = tp * 128 + 128;
        const int ohi = tp * 128 + 7936;   // 1952 groups of 4
        for (int o = olo + tid * 4; o < ohi; o += 2048) {
            const int s  = o + SPAD;
            const int tb = s >> 7;
            const int nb = s & (HOPSZ - 1);
            float y0 = 0.f, y1 = 0.f, y2 = 0.f, y3 = 0.f;
            #pragma unroll
            for (int r = 0; r < 4; ++r) {
                const int lt = tb - r - tp;            // 0..63 by construction
                const int n  = nb + (r << 7);
                ushort4 fv = *(const ushort4*)((const unsigned short*)(smem + lt * (FROW * 2)) + n);
                float4  wv = *(const float4*)(wL + n);
                const float c = XreL[lt] * (1.0f / 512.0f);   // s even -> +,-,+,-
                y0 += bf2f(fv.x) + c * wv.x;
                y1 += bf2f(fv.y) - c * wv.y;
                y2 += bf2f(fv.z) + c * wv.z;
                y3 += bf2f(fv.w) - c * wv.w;
            }
            const float4 er = *(const float4*)(ErcpL + nb);
            *(float4*)(outb + o) = make_float4(y0 * er.x, y1 * er.y, y2 * er.z, y3 * er.w);
        }
    } else {
        // edge panels: R12-verified scalar path with boundary masking
        const int olo = (panel == 0) ? 0 : tp * 128 + 128;
        const int ohi = (panel == NPANEL - 1) ? OUTLEN : tp * 128 + 7936;
        for (int o = olo + tid; o < ohi; o += 512) {
            const int s  = o + SPAD;
            const int tb = s >> 7;
            const int nb = s & (HOPSZ - 1);
            const float sg = (s & 1) ? (-1.0f / 512.0f) : (1.0f / 512.0f);
            float y = 0.f, e = 0.f;
            #pragma unroll
            for (int r = 0; r < 4; ++r) {
                const int t  = tb - r;
                const int lt = t - tp;
                if ((unsigned)lt >= 64u || (unsigned)t >= (unsigned)TFR) continue;
                const int n = nb + (r << 7);
                const float wv = wL[n];
                const float fv = bf2f(*((const unsigned short*)(smem + lt * (FROW * 2)) + n));
                y += fv + sg * XreL[lt] * wv;
                e += wv * wv;
            }
            outb[o] = y / e;
        }
    }
}

// ---------------------------------------------------------------------------
extern "C" void kernel_launch(void* const* d_in, const int* in_sizes, int n_in,
                              void* d_out, int out_size, void* d_ws, size_t ws_size,
                              hipStream_t stream) {
    (void)in_sizes; (void)n_in; (void)out_size; (void)ws_size;
    const float* X   = (const float*)d_in[0];
    const float* wnd = (const float*)d_in[1];
    float* out = (float*)d_out;

    uint4* Wf = (uint4*)d_ws;                                            // 544 KB

    k_wgen<<<136, 256, 0, stream>>>(wnd, Wf);
    k_fused<<<NBC * NPANEL, 512, 0, stream>>>(X, Wf, wnd, out);
}